// Round 8
// baseline (92.734 us; speedup 1.0000x reference)
//
#include <hip/hip_runtime.h>
#include <hip/hip_fp16.h>

#define CDIM 512
#define ROWS 65536

typedef _Float16 half8  __attribute__((ext_vector_type(8)));
typedef __fp16   fp16x2 __attribute__((ext_vector_type(2)));
typedef float    f32x16 __attribute__((ext_vector_type(16)));

// async global->LDS, 16B per lane; LDS dest = wave-uniform base + lane*16
#define GLD_LDS16(gp, lp) __builtin_amdgcn_global_load_lds( \
    (const __attribute__((address_space(1))) unsigned int*)(gp), \
    (__attribute__((address_space(3))) unsigned int*)(lp), 16, 0, 0)

__device__ __forceinline__ half8 cvt8(float4 f0, float4 f1) {
    union { fp16x2 h2[4]; half8 h8; } u;
    u.h2[0] = __builtin_amdgcn_cvt_pkrtz(f0.x, f0.y);
    u.h2[1] = __builtin_amdgcn_cvt_pkrtz(f0.z, f0.w);
    u.h2[2] = __builtin_amdgcn_cvt_pkrtz(f1.x, f1.y);
    u.h2[3] = __builtin_amdgcn_cvt_pkrtz(f1.z, f1.w);
    return u.h8;
}

// ---------------- K1a: v[j] = relu(Q . Wq[j,:] + bq[j]) * Wout[j/64] / 8 ----------------
__global__ void qproj_kernel(const float* __restrict__ Q, const float* __restrict__ Wq,
                             const float* __restrict__ bq, const float* __restrict__ Wout,
                             float* __restrict__ v) {
    __shared__ float qs[CDIM];
    const int t = threadIdx.x;
    qs[t] = Q[t]; qs[t + 256] = Q[t + 256];
    __syncthreads();
    const int jj  = t >> 4;
    const int sub = t & 15;
    const int j   = blockIdx.x * 16 + jj;
    const float4* w4 = (const float4*)(Wq + (size_t)j * CDIM + sub * 32);
    const float4* q4 = (const float4*)(qs + sub * 32);
    float s = 0.f;
    #pragma unroll
    for (int i = 0; i < 8; ++i) {
        float4 w = w4[i]; float4 q = q4[i];
        s = fmaf(w.x, q.x, s); s = fmaf(w.y, q.y, s);
        s = fmaf(w.z, q.z, s); s = fmaf(w.w, q.w, s);
    }
    s += __shfl_xor(s, 1); s += __shfl_xor(s, 2);
    s += __shfl_xor(s, 4); s += __shfl_xor(s, 8);
    if (sub == 0) {
        s += bq[j];
        s = fmaxf(s, 0.f);
        v[j] = s * Wout[j >> 6] * 0.125f;   // 1/sqrt(64) folded; bout dropped (shift-invariant)
    }
}

// ---------------- K1b: Wk -> fp16 B-fragments [jb 0..15][kc 0..31][lane 0..63][8 halfs] ----
// Fragment (jb,kc), lane l: B[k = kc*16 + (l>>5)*8 + e][j = jb*32 + (l&31)]
__global__ void wkfrag_kernel(const float* __restrict__ Wk, _Float16* __restrict__ Wkf) {
    const int gid = blockIdx.x * 256 + threadIdx.x;   // 32768 half8 slots
    const int jb  = gid >> 11;
    const int kc  = (gid >> 6) & 31;
    const int l   = gid & 63;
    const int j   = jb * 32 + (l & 31);
    const int k   = kc * 16 + (l >> 5) * 8;
    const float* src = Wk + (size_t)j * CDIM + k;
    float4 f0 = *(const float4*)(src);
    float4 f1 = *(const float4*)(src + 4);
    *(half8*)(Wkf + (size_t)gid * 8) = cvt8(f0, f1);
}

// ---------------- K2: A-in-regs (32 rows/wave, full depth), B-in-LDS (128j x 512k fp16) ----
// grid 256 = 128 rowblocks x 2 classes (partners adjacent -> L3-served duplicate K reads).
// 8 waves x 64 rows each (2 tiles of 32). B-LDS zigzag: t0:(jh0,jh1), t1:(jh1,jh0) ->
// 2 swaps, 4 barriers per WG total. All LDS accesses fragment-linear: zero bank conflicts.
__global__ __launch_bounds__(512, 2) void score_kernel(
    const float* __restrict__ Kmat, const _Float16* __restrict__ Wkf,
    const float* __restrict__ bk, const float* __restrict__ v,
    float* __restrict__ partial2)
{
    __shared__ alignas(16) char Blds[131072];   // 128 frags x 1KB

    const int tid  = threadIdx.x;
    const int lane = tid & 63;
    const int wave = tid >> 6;
    const int l31  = lane & 31;
    const int lhi  = lane >> 5;
    const int bid  = blockIdx.x;
    const int cls  = bid & 1;
    const int rowblock = bid >> 1;

    const int wrow = rowblock * 512 + wave * 64;    // this wave's 64 rows
    float* pbase = partial2 + (size_t)cls * ROWS;

    const char* wkf0 = (const char*)Wkf + (size_t)(cls * 8 + 0) * 32768;  // jh0: 4 jb blocks
    const char* wkf1 = (const char*)Wkf + (size_t)(cls * 8 + 4) * 32768;  // jh1

#define SWAPB(src) { \
    _Pragma("unroll") for (int i = 0; i < 16; ++i) \
        GLD_LDS16((src) + (size_t)i * 8192 + tid * 16, Blds + i * 8192 + tid * 16); }

    half8 a[32];
#define LOADA(rb) { \
    const float* ab = Kmat + (size_t)((rb) + l31) * CDIM + lhi * 8;       \
    _Pragma("unroll") for (int g = 0; g < 8; ++g) {                        \
        float4 f[8];                                                       \
        _Pragma("unroll") for (int q = 0; q < 4; ++q) {                    \
            f[2*q]   = *(const float4*)(ab + (g*4+q) * 16);                \
            f[2*q+1] = *(const float4*)(ab + (g*4+q) * 16 + 4);            \
        }                                                                  \
        _Pragma("unroll") for (int q = 0; q < 4; ++q)                      \
            a[g*4+q] = cvt8(f[2*q], f[2*q+1]);                             \
    } }

    float part[16];

#define DOPHASE(h) { \
    for (int jbl = 0; jbl < 4; ++jbl) {                                             \
        const int jg = cls * 256 + (h) * 128 + jbl * 32 + l31;                      \
        const float bj = bk[jg];                                                    \
        const float vj = v[jg];                                                     \
        f32x16 acc0, acc1;                                                          \
        _Pragma("unroll") for (int r = 0; r < 16; ++r) { acc0[r] = 0.f; acc1[r] = 0.f; } \
        _Pragma("unroll") for (int kc = 0; kc < 32; kc += 2) {                      \
            half8 b0 = *(const half8*)(Blds + (((jbl*32 + kc    ) * 64 + lane) << 4)); \
            half8 b1 = *(const half8*)(Blds + (((jbl*32 + kc + 1) * 64 + lane) << 4)); \
            acc0 = __builtin_amdgcn_mfma_f32_32x32x16_f16(a[kc],     b0, acc0, 0, 0, 0); \
            acc1 = __builtin_amdgcn_mfma_f32_32x32x16_f16(a[kc + 1], b1, acc1, 0, 0, 0); \
        }                                                                           \
        _Pragma("unroll") for (int r = 0; r < 16; ++r)                              \
            part[r] += fmaxf(acc0[r] + acc1[r] + bj, 0.f) * vj;                     \
    } }

    // fold-tree over the 32 j-lanes (verified in R7); lanes l31<16 hold rows
#define TREESTORE(dst) { \
    float q0[8];                                                                    \
    _Pragma("unroll") for (int i = 0; i < 8; ++i) {                                 \
        const bool b = lane & 1;                                                    \
        float keep = b ? part[i + 8] : part[i];                                     \
        float send = b ? part[i] : part[i + 8];                                     \
        q0[i] = keep + __shfl_xor(send, 1);                                         \
    }                                                                               \
    float q1[4];                                                                    \
    _Pragma("unroll") for (int i = 0; i < 4; ++i) {                                 \
        const bool b = lane & 2;                                                    \
        float keep = b ? q0[i + 4] : q0[i];                                         \
        float send = b ? q0[i] : q0[i + 4];                                         \
        q1[i] = keep + __shfl_xor(send, 2);                                         \
    }                                                                               \
    float q2[2];                                                                    \
    _Pragma("unroll") for (int i = 0; i < 2; ++i) {                                 \
        const bool b = lane & 4;                                                    \
        float keep = b ? q1[i + 2] : q1[i];                                         \
        float send = b ? q1[i] : q1[i + 2];                                         \
        q2[i] = keep + __shfl_xor(send, 4);                                         \
    }                                                                               \
    float q3;                                                                       \
    { const bool b = lane & 8;                                                      \
      float keep = b ? q2[1] : q2[0];                                               \
      float send = b ? q2[0] : q2[1];                                               \
      q3 = keep + __shfl_xor(send, 8); }                                            \
    float s = q3 + __shfl_xor(q3, 16);                                              \
    if (l31 < 16) {                                                                 \
        const int rr  = ((l31 & 1) << 3) | ((l31 & 2) << 1) | ((l31 & 4) >> 1) | ((l31 & 8) >> 3); \
        const int row = (rr & 3) + 8 * (rr >> 2) + 4 * lhi;                         \
        (dst)[row] = s;                                                             \
    } }

    // ---- prologue: B(jh0) via async DMA, overlapped with tile-0 A load ----
    SWAPB(wkf0);
    LOADA(wrow);
    __syncthreads();

    // ---- tile 0 ----
    #pragma unroll
    for (int r = 0; r < 16; ++r) part[r] = 0.f;
    DOPHASE(0);
    __syncthreads();
    SWAPB(wkf1);
    __syncthreads();
    DOPHASE(1);
    TREESTORE(pbase + wrow);

    // ---- tile 1 (B-LDS already holds jh1) ----
    LOADA(wrow + 32);
    #pragma unroll
    for (int r = 0; r < 16; ++r) part[r] = 0.f;
    DOPHASE(1);
    __syncthreads();
    SWAPB(wkf0);
    __syncthreads();
    DOPHASE(0);
    TREESTORE(pbase + wrow + 32);
}

// ---------------- K3: merge 2 classes, store logits, per-block exp-sum ----------------
__global__ void expsum_kernel(const float* __restrict__ partial2, float* __restrict__ logits,
                              float* __restrict__ blocksum) {
    __shared__ float red[256];
    const int t = threadIdx.x;
    const int row = blockIdx.x * 256 + t;
    const float lg = partial2[row] + partial2[ROWS + row];
    logits[row] = lg;
    red[t] = expf(lg);
    __syncthreads();
    for (int s = 128; s > 0; s >>= 1) {
        if (t < s) red[t] += red[t + s];
        __syncthreads();
    }
    if (t == 0) blocksum[blockIdx.x] = red[0];
}

// ---------------- K4: normalize ----------------
__global__ void norm_kernel(const float* __restrict__ logits, const float* __restrict__ blocksum,
                            float* __restrict__ out) {
    __shared__ float red[256];
    const int t = threadIdx.x;
    red[t] = blocksum[t];
    __syncthreads();
    for (int s = 128; s > 0; s >>= 1) {
        if (t < s) red[t] += red[t + s];
        __syncthreads();
    }
    const float zinv = 1.0f / red[0];
    const int i = blockIdx.x * 256 + t;
    out[i] = expf(logits[i]) * zinv;
}

extern "C" void kernel_launch(void* const* d_in, const int* in_sizes, int n_in,
                              void* d_out, int out_size, void* d_ws, size_t ws_size,
                              hipStream_t stream) {
    const float* Q    = (const float*)d_in[0];
    const float* Kmat = (const float*)d_in[1];
    const float* Wq   = (const float*)d_in[2];
    const float* bq   = (const float*)d_in[3];
    const float* Wk   = (const float*)d_in[4];
    const float* bk   = (const float*)d_in[5];
    const float* Wout = (const float*)d_in[6];
    float* out = (float*)d_out;

    char* ws = (char*)d_ws;
    _Float16* Wkf   = (_Float16*)(ws);                // 524288 B
    float* v        = (float*)(ws + 524288);          //   2048 B
    float* partial2 = (float*)(ws + 526336);          // 524288 B (2 classes x 65536)
    float* logits   = (float*)(ws + 1050624);         // 262144 B
    float* blocksum = (float*)(ws + 1312768);         //   1024 B

    hipLaunchKernelGGL(qproj_kernel,  dim3(32),   dim3(256), 0, stream, Q, Wq, bq, Wout, v);
    hipLaunchKernelGGL(wkfrag_kernel, dim3(128),  dim3(256), 0, stream, Wk, Wkf);
    hipLaunchKernelGGL(score_kernel,  dim3(256),  dim3(512), 0, stream, Kmat, Wkf, bk, v, partial2);
    hipLaunchKernelGGL(expsum_kernel, dim3(256),  dim3(256), 0, stream, partial2, logits, blocksum);
    hipLaunchKernelGGL(norm_kernel,   dim3(256),  dim3(256), 0, stream, logits, blocksum, out);
}

// Round 9
// 62.856 us; speedup vs baseline: 1.4754x; 1.4754x over previous
//
#include <hip/hip_runtime.h>
#include <hip/hip_fp16.h>

#define CDIM 512
#define ROWS 65536
#define TPW  16     // 32-row tiles per WG; 128 rowblocks x 16 x 32 = 65536

typedef _Float16 half8  __attribute__((ext_vector_type(8)));
typedef __fp16   fp16x2 __attribute__((ext_vector_type(2)));
typedef float    f32x16 __attribute__((ext_vector_type(16)));

__device__ __forceinline__ half8 cvt8(float4 f0, float4 f1) {
    union { fp16x2 h2[4]; half8 h8; } u;
    u.h2[0] = __builtin_amdgcn_cvt_pkrtz(f0.x, f0.y);
    u.h2[1] = __builtin_amdgcn_cvt_pkrtz(f0.z, f0.w);
    u.h2[2] = __builtin_amdgcn_cvt_pkrtz(f1.x, f1.y);
    u.h2[3] = __builtin_amdgcn_cvt_pkrtz(f1.z, f1.w);
    return u.h8;
}

// ---------------- K1a: v[j] = relu(Q . Wq[j,:] + bq[j]) * Wout[j/64] / 8 ----------------
__global__ void qproj_kernel(const float* __restrict__ Q, const float* __restrict__ Wq,
                             const float* __restrict__ bq, const float* __restrict__ Wout,
                             float* __restrict__ v) {
    __shared__ float qs[CDIM];
    const int t = threadIdx.x;
    qs[t] = Q[t]; qs[t + 256] = Q[t + 256];
    __syncthreads();
    const int jj  = t >> 4;
    const int sub = t & 15;
    const int j   = blockIdx.x * 16 + jj;
    const float4* w4 = (const float4*)(Wq + (size_t)j * CDIM + sub * 32);
    const float4* q4 = (const float4*)(qs + sub * 32);
    float s = 0.f;
    #pragma unroll
    for (int i = 0; i < 8; ++i) {
        float4 w = w4[i]; float4 q = q4[i];
        s = fmaf(w.x, q.x, s); s = fmaf(w.y, q.y, s);
        s = fmaf(w.z, q.z, s); s = fmaf(w.w, q.w, s);
    }
    s += __shfl_xor(s, 1); s += __shfl_xor(s, 2);
    s += __shfl_xor(s, 4); s += __shfl_xor(s, 8);
    if (sub == 0) {
        s += bq[j];
        s = fmaxf(s, 0.f);
        v[j] = s * Wout[j >> 6] * 0.125f;   // 1/sqrt(64) folded; bout dropped (shift-invariant)
    }
}

// ---------------- K1b: Wk -> fp16 B-fragments [jb 0..15][kc 0..31][lane 0..63][8 halfs] ----
// Fragment (jb,kc), lane l: B[k = kc*16 + (l>>5)*8 + e][j = jb*32 + (l&31)]
__global__ void wkfrag_kernel(const float* __restrict__ Wk, _Float16* __restrict__ Wkf) {
    const int gid = blockIdx.x * 256 + threadIdx.x;   // 32768 half8 slots
    const int jb  = gid >> 11;
    const int kc  = (gid >> 6) & 31;
    const int l   = gid & 63;
    const int j   = jb * 32 + (l & 31);
    const int k   = kc * 16 + (l >> 5) * 8;
    const float* src = Wk + (size_t)j * CDIM + k;
    float4 f0 = *(const float4*)(src);
    float4 f1 = *(const float4*)(src + 4);
    *(half8*)(Wkf + (size_t)gid * 8) = cvt8(f0, f1);
}

// ---------------- K2: B-in-regs (32 j/wave), frag-major fp16 A-tiles in LDS -----------
// 256 WGs = 128 rowblocks x 2 classes (same-XCD partners: bid, bid+8). 8 waves x 512 thr.
// Per 32-row tile: wave reads 32 frags (contiguous 1KB each, conflict-free) x 32 MFMA.
// Staging: thread owns 4 frag-slots (wave w -> frags 4w..4w+3): strided global loads,
// cvt_pkrtz, contiguous frag writes. Write-late + sched_barrier; 1 barrier per tile.
__global__ __launch_bounds__(512, 2) void score_kernel(
    const float* __restrict__ Kmat, const _Float16* __restrict__ Wkf,
    const float* __restrict__ bk, const float* __restrict__ v,
    float* __restrict__ partial2)
{
    __shared__ alignas(16) char fragbuf[2][32768];   // 2 x (32 kc x 64 lanes x 16B)
    __shared__ float scratch2[2][8][32];

    const int tid  = threadIdx.x;
    const int lane = tid & 63;
    const int wave = tid >> 6;
    const int l31  = lane & 31;
    const int lhi  = lane >> 5;

    const int bid      = blockIdx.x;
    const int cls      = (bid >> 3) & 1;
    const int rowblock = (bid & 7) * 16 + (bid >> 4);   // partners bid, bid+8: same XCD
    const int rowbase  = rowblock * (TPW * 32);
    const int jb       = cls * 8 + wave;
    float* pbase = partial2 + (size_t)cls * ROWS;

    // ---- B prologue: 32 resident fragments (full depth, this wave's 32 j's) ----
    half8 B[32];
    const half8* bsrc = (const half8*)Wkf + (size_t)jb * 2048 + lane;
    #pragma unroll
    for (int kc = 0; kc < 32; ++kc) B[kc] = bsrc[kc * 64];
    const int jmy = jb * 32 + l31;
    const float bj = bk[jmy];
    const float vj = v[jmy];

    // staging geometry: thread owns frag-slots (kc0+i, slot=tid&63), i=0..3
    const int kc0  = wave * 4;
    const int srow = tid & 31;
    const int slhi = (tid >> 5) & 1;
    const int slot = tid & 63;

    // ---- prologue: stage tile 0 ----
    {
        const float* g0 = Kmat + (size_t)(rowbase + srow) * CDIM + kc0 * 16 + slhi * 8;
        #pragma unroll
        for (int i = 0; i < 4; ++i) {
            float4 f0 = *(const float4*)(g0 + i * 16);
            float4 f1 = *(const float4*)(g0 + i * 16 + 4);
            *(half8*)(&fragbuf[0][(kc0 + i) * 1024 + slot * 16]) = cvt8(f0, f1);
        }
    }
    __syncthreads();

    for (int t = 0; t < TPW; ++t) {
        const int cur = t & 1;
        const bool pf = (t + 1 < TPW);
        const char* sb = fragbuf[cur];
        char* db = fragbuf[cur ^ 1];
        const float* gt = Kmat + (size_t)(rowbase + (pf ? (t + 1) : t) * 32 + srow) * CDIM
                        + kc0 * 16 + slhi * 8;

        // lagged cross-wave summer for tile t-1
        if (t > 0 && tid < 32) {
            const int pt = (t - 1) & 1;
            float s = 0.f;
            #pragma unroll
            for (int w = 0; w < 8; ++w) s += scratch2[pt][w][tid];
            pbase[rowbase + (t - 1) * 32 + tid] = s;
        }

        f32x16 acc0, acc1;
        #pragma unroll
        for (int r = 0; r < 16; ++r) { acc0[r] = 0.f; acc1[r] = 0.f; }

        // ---- issue loads for slots 0,1 of t+1 ----
        float4 L0, L1, L2, L3;
        if (pf) {
            L0 = *(const float4*)(gt);
            L1 = *(const float4*)(gt + 4);
            L2 = *(const float4*)(gt + 16);
            L3 = *(const float4*)(gt + 20);
        }
        __builtin_amdgcn_sched_barrier(0);

        // ---- compute kc 0..15 (frag reads: contiguous 1KB per wave, conflict-free) ----
        #pragma unroll
        for (int kc = 0; kc < 16; kc += 2) {
            half8 a0 = *(const half8*)(sb + kc * 1024 + lane * 16);
            half8 a1 = *(const half8*)(sb + (kc + 1) * 1024 + lane * 16);
            acc0 = __builtin_amdgcn_mfma_f32_32x32x16_f16(a0, B[kc],     acc0, 0, 0, 0);
            acc1 = __builtin_amdgcn_mfma_f32_32x32x16_f16(a1, B[kc + 1], acc1, 0, 0, 0);
        }

        // ---- write slots 0,1; issue loads for slots 2,3 ----
        if (pf) {
            *(half8*)(db + (kc0 + 0) * 1024 + slot * 16) = cvt8(L0, L1);
            *(half8*)(db + (kc0 + 1) * 1024 + slot * 16) = cvt8(L2, L3);
            L0 = *(const float4*)(gt + 32);
            L1 = *(const float4*)(gt + 36);
            L2 = *(const float4*)(gt + 48);
            L3 = *(const float4*)(gt + 52);
        }
        __builtin_amdgcn_sched_barrier(0);

        // ---- compute kc 16..31 ----
        #pragma unroll
        for (int kc = 16; kc < 32; kc += 2) {
            half8 a0 = *(const half8*)(sb + kc * 1024 + lane * 16);
            half8 a1 = *(const half8*)(sb + (kc + 1) * 1024 + lane * 16);
            acc0 = __builtin_amdgcn_mfma_f32_32x32x16_f16(a0, B[kc],     acc0, 0, 0, 0);
            acc1 = __builtin_amdgcn_mfma_f32_32x32x16_f16(a1, B[kc + 1], acc1, 0, 0, 0);
        }

        // ---- write slots 2,3 ----
        if (pf) {
            *(half8*)(db + (kc0 + 2) * 1024 + slot * 16) = cvt8(L0, L1);
            *(half8*)(db + (kc0 + 3) * 1024 + slot * 16) = cvt8(L2, L3);
        }

        // ---- epilogue: relu + v-weight + fold-tree over 32 j-lanes ----
        {
            float part[16];
            #pragma unroll
            for (int r = 0; r < 16; ++r)
                part[r] = fmaxf(acc0[r] + acc1[r] + bj, 0.f) * vj;

            float q0[8];
            #pragma unroll
            for (int i = 0; i < 8; ++i) {
                const bool b = lane & 1;
                float keep = b ? part[i + 8] : part[i];
                float send = b ? part[i] : part[i + 8];
                q0[i] = keep + __shfl_xor(send, 1);
            }
            float q1[4];
            #pragma unroll
            for (int i = 0; i < 4; ++i) {
                const bool b = lane & 2;
                float keep = b ? q0[i + 4] : q0[i];
                float send = b ? q0[i] : q0[i + 4];
                q1[i] = keep + __shfl_xor(send, 2);
            }
            float q2[2];
            #pragma unroll
            for (int i = 0; i < 2; ++i) {
                const bool b = lane & 4;
                float keep = b ? q1[i + 2] : q1[i];
                float send = b ? q1[i] : q1[i + 2];
                q2[i] = keep + __shfl_xor(send, 4);
            }
            float q3;
            {
                const bool b = lane & 8;
                float keep = b ? q2[1] : q2[0];
                float send = b ? q2[0] : q2[1];
                q3 = keep + __shfl_xor(send, 8);
            }
            float s = q3 + __shfl_xor(q3, 16);
            if (l31 < 16) {
                const int rr  = ((l31 & 1) << 3) | ((l31 & 2) << 1) | ((l31 & 4) >> 1) | ((l31 & 8) >> 3);
                const int row = (rr & 3) + 8 * (rr >> 2) + 4 * lhi;
                scratch2[cur][wave][row] = s;
            }
        }

        __syncthreads();
    }

    // drain: summer for the last tile
    if (tid < 32) {
        const int pt = (TPW - 1) & 1;
        float s = 0.f;
        #pragma unroll
        for (int w = 0; w < 8; ++w) s += scratch2[pt][w][tid];
        pbase[rowbase + (TPW - 1) * 32 + tid] = s;
    }
}

// ---------------- K3: merge 2 classes, store logits, per-block exp-sum ----------------
__global__ void expsum_kernel(const float* __restrict__ partial2, float* __restrict__ logits,
                              float* __restrict__ blocksum) {
    __shared__ float red[256];
    const int t = threadIdx.x;
    const int row = blockIdx.x * 256 + t;
    const float lg = partial2[row] + partial2[ROWS + row];
    logits[row] = lg;
    red[t] = expf(lg);
    __syncthreads();
    for (int s = 128; s > 0; s >>= 1) {
        if (t < s) red[t] += red[t + s];
        __syncthreads();
    }
    if (t == 0) blocksum[blockIdx.x] = red[0];
}

// ---------------- K4: normalize ----------------
__global__ void norm_kernel(const float* __restrict__ logits, const float* __restrict__ blocksum,
                            float* __restrict__ out) {
    __shared__ float red[256];
    const int t = threadIdx.x;
    red[t] = blocksum[t];
    __syncthreads();
    for (int s = 128; s > 0; s >>= 1) {
        if (t < s) red[t] += red[t + s];
        __syncthreads();
    }
    const float zinv = 1.0f / red[0];
    const int i = blockIdx.x * 256 + t;
    out[i] = expf(logits[i]) * zinv;
}

extern "C" void kernel_launch(void* const* d_in, const int* in_sizes, int n_in,
                              void* d_out, int out_size, void* d_ws, size_t ws_size,
                              hipStream_t stream) {
    const float* Q    = (const float*)d_in[0];
    const float* Kmat = (const float*)d_in[1];
    const float* Wq   = (const float*)d_in[2];
    const float* bq   = (const float*)d_in[3];
    const float* Wk   = (const float*)d_in[4];
    const float* bk   = (const float*)d_in[5];
    const float* Wout = (const float*)d_in[6];
    float* out = (float*)d_out;

    char* ws = (char*)d_ws;
    _Float16* Wkf   = (_Float16*)(ws);                // 524288 B
    float* v        = (float*)(ws + 524288);          //   2048 B
    float* partial2 = (float*)(ws + 526336);          // 524288 B (2 classes x 65536)
    float* logits   = (float*)(ws + 1050624);         // 262144 B
    float* blocksum = (float*)(ws + 1312768);         //   1024 B

    hipLaunchKernelGGL(qproj_kernel,  dim3(32),   dim3(256), 0, stream, Q, Wq, bq, Wout, v);
    hipLaunchKernelGGL(wkfrag_kernel, dim3(128),  dim3(256), 0, stream, Wk, Wkf);
    hipLaunchKernelGGL(score_kernel,  dim3(256),  dim3(512), 0, stream, Kmat, Wkf, bk, v, partial2);
    hipLaunchKernelGGL(expsum_kernel, dim3(256),  dim3(256), 0, stream, partial2, logits, blocksum);
    hipLaunchKernelGGL(norm_kernel,   dim3(256),  dim3(256), 0, stream, logits, blocksum, out);
}

// Round 10
// 61.898 us; speedup vs baseline: 1.4982x; 1.0155x over previous
//
#include <hip/hip_runtime.h>
#include <hip/hip_fp16.h>

#define CDIM 512
#define ROWS 65536
#define TPW  16     // 32-row tiles per WG; 128 rowblocks x 16 x 32 = 65536

typedef _Float16 half8  __attribute__((ext_vector_type(8)));
typedef __fp16   fp16x2 __attribute__((ext_vector_type(2)));
typedef float    f32x16 __attribute__((ext_vector_type(16)));

__device__ __forceinline__ half8 cvt8(float4 f0, float4 f1) {
    union { fp16x2 h2[4]; half8 h8; } u;
    u.h2[0] = __builtin_amdgcn_cvt_pkrtz(f0.x, f0.y);
    u.h2[1] = __builtin_amdgcn_cvt_pkrtz(f0.z, f0.w);
    u.h2[2] = __builtin_amdgcn_cvt_pkrtz(f1.x, f1.y);
    u.h2[3] = __builtin_amdgcn_cvt_pkrtz(f1.z, f1.w);
    return u.h8;
}

// ---------------- K1 (fused): blocks 0..31 qproj, blocks 32..159 wkfrag ----------------
__global__ void prep_kernel(const float* __restrict__ Q, const float* __restrict__ Wq,
                            const float* __restrict__ bq, const float* __restrict__ Wout,
                            const float* __restrict__ Wk,
                            float* __restrict__ v, _Float16* __restrict__ Wkf) {
    __shared__ float qs[CDIM];
    const int t = threadIdx.x;
    if (blockIdx.x < 32) {
        // v[j] = relu(Q.Wq[j,:]+bq[j]) * Wout[j/64] / 8 ; bout dropped (softmax shift-invariant)
        qs[t] = Q[t]; qs[t + 256] = Q[t + 256];
        __syncthreads();
        const int jj  = t >> 4;
        const int sub = t & 15;
        const int j   = blockIdx.x * 16 + jj;
        const float4* w4 = (const float4*)(Wq + (size_t)j * CDIM + sub * 32);
        const float4* q4 = (const float4*)(qs + sub * 32);
        float s = 0.f;
        #pragma unroll
        for (int i = 0; i < 8; ++i) {
            float4 w = w4[i]; float4 q = q4[i];
            s = fmaf(w.x, q.x, s); s = fmaf(w.y, q.y, s);
            s = fmaf(w.z, q.z, s); s = fmaf(w.w, q.w, s);
        }
        s += __shfl_xor(s, 1); s += __shfl_xor(s, 2);
        s += __shfl_xor(s, 4); s += __shfl_xor(s, 8);
        if (sub == 0) {
            s += bq[j];
            s = fmaxf(s, 0.f);
            v[j] = s * Wout[j >> 6] * 0.125f;
        }
    } else {
        // Wk -> fp16 B-fragments [jb][kc][lane][8]; frag(jb,kc) lane l:
        // B[k=kc*16+(l>>5)*8+e][j=jb*32+(l&31)]
        const int gid = (blockIdx.x - 32) * 256 + t;
        const int jb  = gid >> 11;
        const int kc  = (gid >> 6) & 31;
        const int l   = gid & 63;
        const int j   = jb * 32 + (l & 31);
        const int k   = kc * 16 + (l >> 5) * 8;
        const float* src = Wk + (size_t)j * CDIM + k;
        float4 f0 = *(const float4*)(src);
        float4 f1 = *(const float4*)(src + 4);
        *(half8*)(Wkf + (size_t)gid * 8) = cvt8(f0, f1);
    }
}

// ---------------- K2: 64 j/wave (B0+B1 resident, 256 VGPRs), 4-wave WG ----------------
// 256 WGs = 128 rowblocks x 2 classes (partners bid,bid+8 share XCD/L2). 1 wave/SIMD.
// Per 32-row tile: 32 ds_read_b128 feed 64 MFMAs (each read used by 2 j-blocks).
// Quarter-pipelined staging: 2 reg sets; issue q+1 loads before computing q; write set q
// after; next tile's set 0 issued before the epilogue tree. sched_barrier pins phases.
__global__ __launch_bounds__(256, 1) void score_kernel(
    const float* __restrict__ Kmat, const _Float16* __restrict__ Wkf,
    const float* __restrict__ bk, const float* __restrict__ v,
    float* __restrict__ partial2)
{
    __shared__ alignas(16) char fragbuf[2][32768];   // 2 x (32 kc x 64 lanes x 16B)
    __shared__ float scratch2[2][4][32];

    const int tid  = threadIdx.x;
    const int lane = tid & 63;
    const int wave = tid >> 6;          // 0..3
    const int l31  = lane & 31;
    const int lhi  = lane >> 5;

    const int bid      = blockIdx.x;
    const int cls      = (bid >> 3) & 1;
    const int rowblock = (bid & 7) * 16 + (bid >> 4);   // partners bid, bid+8: same XCD
    const int rowbase  = rowblock * (TPW * 32);
    float* pbase = partial2 + (size_t)cls * ROWS;

    // ---- B prologue: two resident j-blocks (full depth) ----
    half8 B0[32], B1[32];
    {
        const half8* b0 = (const half8*)Wkf + (size_t)(cls * 8 + wave) * 2048 + lane;
        const half8* b1 = (const half8*)Wkf + (size_t)(cls * 8 + 4 + wave) * 2048 + lane;
        #pragma unroll
        for (int kc = 0; kc < 32; ++kc) { B0[kc] = b0[kc * 64]; B1[kc] = b1[kc * 64]; }
    }
    const int j0 = (cls * 8 + wave) * 32 + l31;
    const int j1 = (cls * 8 + 4 + wave) * 32 + l31;
    const float bj0 = bk[j0], vj0 = v[j0];
    const float bj1 = bk[j1], vj1 = v[j1];

    // staging: thread (lane, wave) owns frags {q*8+wave, q*8+4+wave} at slot=lane
    const int srow = lane & 31;
    const int skof = (lane >> 5) * 8;

    // ---- prologue: stage tile 0 fully ----
    {
        const float* g0 = Kmat + (size_t)(rowbase + srow) * CDIM + skof;
        #pragma unroll
        for (int q = 0; q < 4; ++q) {
            #pragma unroll
            for (int h = 0; h < 2; ++h) {
                const int kc = q * 8 + h * 4 + wave;
                float4 f0 = *(const float4*)(g0 + kc * 16);
                float4 f1 = *(const float4*)(g0 + kc * 16 + 4);
                *(half8*)(&fragbuf[0][kc * 1024 + lane * 16]) = cvt8(f0, f1);
            }
        }
    }

    float4 L[2][4];
    // pre-issue set 0 (tile 1's frags {wave, 4+wave}) before the first barrier
    {
        const float* g1 = Kmat + (size_t)(rowbase + 32 + srow) * CDIM + skof;
        L[0][0] = *(const float4*)(g1 + wave * 16);
        L[0][1] = *(const float4*)(g1 + wave * 16 + 4);
        L[0][2] = *(const float4*)(g1 + (4 + wave) * 16);
        L[0][3] = *(const float4*)(g1 + (4 + wave) * 16 + 4);
    }
    __syncthreads();

    for (int t = 0; t < TPW; ++t) {
        const int cur = t & 1;
        const bool pf = (t + 1 < TPW);
        const char* sb = fragbuf[cur];
        char* db = fragbuf[cur ^ 1];
        const float* gt = Kmat + (size_t)(rowbase + (t + 1) * 32 + srow) * CDIM + skof;

        // lagged cross-wave summer for tile t-1
        if (t > 0 && tid < 32) {
            const int pt = (t - 1) & 1;
            float s = scratch2[pt][0][tid] + scratch2[pt][1][tid]
                    + scratch2[pt][2][tid] + scratch2[pt][3][tid];
            pbase[rowbase + (t - 1) * 32 + tid] = s;
        }

        f32x16 acc0, acc1;
        #pragma unroll
        for (int r = 0; r < 16; ++r) { acc0[r] = 0.f; acc1[r] = 0.f; }

        #pragma unroll
        for (int q = 0; q < 4; ++q) {
            if (pf && q < 3) {   // issue loads for quarter q+1 (1-quarter cover)
                const int kcA = (q + 1) * 8 + wave;
                const int kcB = (q + 1) * 8 + 4 + wave;
                L[(q + 1) & 1][0] = *(const float4*)(gt + kcA * 16);
                L[(q + 1) & 1][1] = *(const float4*)(gt + kcA * 16 + 4);
                L[(q + 1) & 1][2] = *(const float4*)(gt + kcB * 16);
                L[(q + 1) & 1][3] = *(const float4*)(gt + kcB * 16 + 4);
            }
            __builtin_amdgcn_sched_barrier(0);
            #pragma unroll
            for (int i = 0; i < 8; ++i) {
                const int kc = q * 8 + i;
                half8 a = *(const half8*)(sb + kc * 1024 + lane * 16);
                acc0 = __builtin_amdgcn_mfma_f32_32x32x16_f16(a, B0[kc], acc0, 0, 0, 0);
                acc1 = __builtin_amdgcn_mfma_f32_32x32x16_f16(a, B1[kc], acc1, 0, 0, 0);
            }
            if (pf) {            // write set q (issued one quarter ago)
                const int kcA = q * 8 + wave;
                const int kcB = q * 8 + 4 + wave;
                *(half8*)(db + kcA * 1024 + lane * 16) = cvt8(L[q & 1][0], L[q & 1][1]);
                *(half8*)(db + kcB * 1024 + lane * 16) = cvt8(L[q & 1][2], L[q & 1][3]);
            }
            __builtin_amdgcn_sched_barrier(0);
        }

        // pre-issue set 0 for NEXT tile's staging (covers under tree+barrier+summer)
        if (t + 2 < TPW) {
            const float* gn = gt + 32 * CDIM;
            L[0][0] = *(const float4*)(gn + wave * 16);
            L[0][1] = *(const float4*)(gn + wave * 16 + 4);
            L[0][2] = *(const float4*)(gn + (4 + wave) * 16);
            L[0][3] = *(const float4*)(gn + (4 + wave) * 16 + 4);
        }
        __builtin_amdgcn_sched_barrier(0);

        // ---- epilogue: relu + v-weight (both j-blocks), fold-tree over 32 j-lanes ----
        {
            float part[16];
            #pragma unroll
            for (int r = 0; r < 16; ++r)
                part[r] = fmaxf(acc0[r] + bj0, 0.f) * vj0 + fmaxf(acc1[r] + bj1, 0.f) * vj1;

            float q0[8];
            #pragma unroll
            for (int i = 0; i < 8; ++i) {
                const bool b = lane & 1;
                float keep = b ? part[i + 8] : part[i];
                float send = b ? part[i] : part[i + 8];
                q0[i] = keep + __shfl_xor(send, 1);
            }
            float q1[4];
            #pragma unroll
            for (int i = 0; i < 4; ++i) {
                const bool b = lane & 2;
                float keep = b ? q0[i + 4] : q0[i];
                float send = b ? q0[i] : q0[i + 4];
                q1[i] = keep + __shfl_xor(send, 2);
            }
            float q2[2];
            #pragma unroll
            for (int i = 0; i < 2; ++i) {
                const bool b = lane & 4;
                float keep = b ? q1[i + 2] : q1[i];
                float send = b ? q1[i] : q1[i + 2];
                q2[i] = keep + __shfl_xor(send, 4);
            }
            float q3;
            {
                const bool b = lane & 8;
                float keep = b ? q2[1] : q2[0];
                float send = b ? q2[0] : q2[1];
                q3 = keep + __shfl_xor(send, 8);
            }
            float s = q3 + __shfl_xor(q3, 16);
            if (l31 < 16) {
                const int rr  = ((l31 & 1) << 3) | ((l31 & 2) << 1) | ((l31 & 4) >> 1) | ((l31 & 8) >> 3);
                const int row = (rr & 3) + 8 * (rr >> 2) + 4 * lhi;
                scratch2[cur][wave][row] = s;
            }
        }

        __syncthreads();
    }

    // drain: summer for the last tile
    if (tid < 32) {
        const int pt = (TPW - 1) & 1;
        float s = scratch2[pt][0][tid] + scratch2[pt][1][tid]
                + scratch2[pt][2][tid] + scratch2[pt][3][tid];
        pbase[rowbase + (TPW - 1) * 32 + tid] = s;
    }
}

// ---------------- K3: merge 2 classes, store logits, per-block exp-sum ----------------
__global__ void expsum_kernel(const float* __restrict__ partial2, float* __restrict__ logits,
                              float* __restrict__ blocksum) {
    __shared__ float red[256];
    const int t = threadIdx.x;
    const int row = blockIdx.x * 256 + t;
    const float lg = partial2[row] + partial2[ROWS + row];
    logits[row] = lg;
    red[t] = expf(lg);
    __syncthreads();
    for (int s = 128; s > 0; s >>= 1) {
        if (t < s) red[t] += red[t + s];
        __syncthreads();
    }
    if (t == 0) blocksum[blockIdx.x] = red[0];
}

// ---------------- K4: normalize ----------------
__global__ void norm_kernel(const float* __restrict__ logits, const float* __restrict__ blocksum,
                            float* __restrict__ out) {
    __shared__ float red[256];
    const int t = threadIdx.x;
    red[t] = blocksum[t];
    __syncthreads();
    for (int s = 128; s > 0; s >>= 1) {
        if (t < s) red[t] += red[t + s];
        __syncthreads();
    }
    const float zinv = 1.0f / red[0];
    const int i = blockIdx.x * 256 + t;
    out[i] = expf(logits[i]) * zinv;
}

extern "C" void kernel_launch(void* const* d_in, const int* in_sizes, int n_in,
                              void* d_out, int out_size, void* d_ws, size_t ws_size,
                              hipStream_t stream) {
    const float* Q    = (const float*)d_in[0];
    const float* Kmat = (const float*)d_in[1];
    const float* Wq   = (const float*)d_in[2];
    const float* bq   = (const float*)d_in[3];
    const float* Wk   = (const float*)d_in[4];
    const float* bk   = (const float*)d_in[5];
    const float* Wout = (const float*)d_in[6];
    float* out = (float*)d_out;

    char* ws = (char*)d_ws;
    _Float16* Wkf   = (_Float16*)(ws);                // 524288 B
    float* v        = (float*)(ws + 524288);          //   2048 B
    float* partial2 = (float*)(ws + 526336);          // 524288 B (2 classes x 65536)
    float* logits   = (float*)(ws + 1050624);         // 262144 B
    float* blocksum = (float*)(ws + 1312768);         //   1024 B

    hipLaunchKernelGGL(prep_kernel,   dim3(160),  dim3(256), 0, stream, Q, Wq, bq, Wout, Wk, v, Wkf);
    hipLaunchKernelGGL(score_kernel,  dim3(256),  dim3(256), 0, stream, Kmat, Wkf, bk, v, partial2);
    hipLaunchKernelGGL(expsum_kernel, dim3(256),  dim3(256), 0, stream, partial2, logits, blocksum);
    hipLaunchKernelGGL(norm_kernel,   dim3(256),  dim3(256), 0, stream, logits, blocksum, out);
}